// Round 8
// baseline (156.866 us; speedup 1.0000x reference)
//
#include <hip/hip_runtime.h>
#include <math.h>

// Shapes (compile-time)
#define BB 16
#define LL 28
#define RR 64
#define DD 512
#define NROLE 512           // role chunks: (r-pair, 64-d slice, e-half)
#define NEVT  256           // evt chunks: (b, 32-wide d range)
#define F4RR  65536         // DD*DD/4 : r-to-r stride in float4 units

// ---------------------------------------------------------------------------
// Kernel A. Lessons baked in: no in-kernel global sync (round-5: ~250us L2
// storms); 3 blocks/CU so all 768 blocks co-resident (round-6: +occupancy);
// e-split for parallelism w/o extra traffic (round-4); k-split per wave so
// WRT is fetched exactly once per block (round-2); 2-dispatch structure
// (round-7: the 3-dispatch tail split cost ~5-7us).
// Micro-opts kept from round-7 (statically-resolved prefetch guard, 3-barrier
// row-split combine) — this round isolates them from the tail-split variable.
// ---------------------------------------------------------------------------
__global__ void __launch_bounds__(256, 3) kernel_a(
    const float* __restrict__ logits,   // [B,L,R]
    const float* __restrict__ arg,      // [B,L,D]
    const float* __restrict__ WRT,      // [R,D,D]
    const float* __restrict__ WTT,      // [E,D,D]
    const float* __restrict__ evt_emb,  // [B,1,D]
    const int*   __restrict__ evt_type, // [B]
    float* __restrict__ part,           // [NROLE][16][256]
    float* __restrict__ evt_part)       // [NEVT][512]
{
    __shared__ float smem[8192];        // 32 KB (G 8KB, combine 32KB)
    const int t   = threadIdx.x;
    const int bid = blockIdx.x;

    if (bid < NROLE) {
        // -------- role chunk: (r-pair rp, d-slice d0, e-half eh) --------
        const int rid = bid;
        const int rp  = rid >> 4;           // [0,32)
        const int d0  = ((rid >> 1) & 7) * 64;
        const int eh  = rid & 1;

        const float4* WBase = (const float4*)(WRT + ((size_t)(2 * rp) * DD + d0) * DD);

        const int e4    = t & 63;           // f4 col within e-half
        const int h     = t >> 6;           // wave id = k-quarter owner
        const int co    = eh * 64 + e4;     // f4 col within full row
        const int kbase = 16 * h;

        // Prefetch WRT batch 0 (this wave's k-rows 0..7 of r0) BEFORE phase 1.
        float4 w[8];
#pragma unroll
        for (int i = 0; i < 8; ++i)
            w[i] = WBase[(size_t)(kbase + i) * 128 + co];

        // Phase 1: G[rr][row][b], row = d-local in [0,64), b in [0,16).
        {
            const int b  = t >> 4;
            const int d4 = t & 15;          // float4 d-group (coalesced arg)
            const float4* ap = (const float4*)(arg) + (size_t)(b * LL) * 128 + (d0 >> 2) + d4;
            const float2* lp = (const float2*)(logits) + (size_t)(b * LL) * 32 + rp;
            float4 g0 = {0.f,0.f,0.f,0.f}, g1 = {0.f,0.f,0.f,0.f};
#pragma unroll 7
            for (int l = 0; l < LL; ++l) {
                const float4 av = ap[(size_t)l * 128];
                const float2 lg = lp[(size_t)l * 32];   // logits[b,l,2rp..2rp+1]
                g0.x = fmaf(lg.x, av.x, g0.x); g0.y = fmaf(lg.x, av.y, g0.y);
                g0.z = fmaf(lg.x, av.z, g0.z); g0.w = fmaf(lg.x, av.w, g0.w);
                g1.x = fmaf(lg.y, av.x, g1.x); g1.y = fmaf(lg.y, av.y, g1.y);
                g1.z = fmaf(lg.y, av.z, g1.z); g1.w = fmaf(lg.y, av.w, g1.w);
            }
            const int row = 4 * d4;
            smem[       (row + 0) * 16 + b] = g0.x;
            smem[       (row + 1) * 16 + b] = g0.y;
            smem[       (row + 2) * 16 + b] = g0.z;
            smem[       (row + 3) * 16 + b] = g0.w;
            smem[1024 + (row + 0) * 16 + b] = g1.x;
            smem[1024 + (row + 1) * 16 + b] = g1.y;
            smem[1024 + (row + 2) * 16 + b] = g1.z;
            smem[1024 + (row + 3) * 16 + b] = g1.w;
        }
        __syncthreads();

        // Phase 2: 4 macro-batches (rr = mb>>1, 8 k-rows each), reg dbuf.
        // Prefetch guarded: NO wrap-around reload on the last batch (guard
        // resolves statically after unroll).
        float4 acc[16];
#pragma unroll
        for (int i = 0; i < 16; ++i) acc[i] = make_float4(0.f, 0.f, 0.f, 0.f);

#pragma unroll
        for (int mb = 0; mb < 4; ++mb) {
            float4 wn[8];
            if (mb < 3) {
                const int mbn = mb + 1;
                const size_t nb = (size_t)(mbn >> 1) * F4RR;
                const int kn = kbase + (mbn & 1) * 8;
#pragma unroll
                for (int i = 0; i < 8; ++i)
                    wn[i] = WBase[nb + (size_t)(kn + i) * 128 + co];
            }
            const float* Gr = smem + (mb >> 1) * 1024;
            const int k0 = kbase + (mb & 1) * 8;
#pragma unroll
            for (int i = 0; i < 8; ++i) {
                const float* gp = Gr + (k0 + i) * 16;
                const float4 ga = ((const float4*)gp)[0];   // uniform b128 bcast
                const float4 gb = ((const float4*)gp)[1];
                const float4 gc = ((const float4*)gp)[2];
                const float4 gd = ((const float4*)gp)[3];
#define ACC(j, S) \
                acc[j].x = fmaf(S, w[i].x, acc[j].x); \
                acc[j].y = fmaf(S, w[i].y, acc[j].y); \
                acc[j].z = fmaf(S, w[i].z, acc[j].z); \
                acc[j].w = fmaf(S, w[i].w, acc[j].w);
                ACC(0,  ga.x) ACC(1,  ga.y) ACC(2,  ga.z) ACC(3,  ga.w)
                ACC(4,  gb.x) ACC(5,  gb.y) ACC(6,  gb.z) ACC(7,  gb.w)
                ACC(8,  gc.x) ACC(9,  gc.y) ACC(10, gc.z) ACC(11, gc.w)
                ACC(12, gd.x) ACC(13, gd.y) ACC(14, gd.z) ACC(15, gd.w)
#undef ACC
            }
            if (mb < 3) {
#pragma unroll
                for (int i = 0; i < 8; ++i) w[i] = wn[i];
            }
        }

        // Combine the 4 k-quarter waves; final store row-split across h0/h1.
        __syncthreads();
        float4* cb = (float4*)smem;                  // 2048 f4 = 32 KB
        if (h >= 2) {
#pragma unroll
            for (int i = 0; i < 16; ++i)
                cb[(h - 2) * 1024 + i * 64 + e4] = acc[i];   // contig: no conflicts
        }
        __syncthreads();
        if (h == 0) {
            // S0 = acc_h0 + acc_h2; publish rows 8..15 into h2 region
#pragma unroll
            for (int i = 0; i < 16; ++i) {
                const float4 v = cb[i * 64 + e4];
                acc[i].x += v.x; acc[i].y += v.y; acc[i].z += v.z; acc[i].w += v.w;
            }
#pragma unroll
            for (int i = 8; i < 16; ++i)
                cb[(i - 8) * 64 + e4] = acc[i];
        } else if (h == 1) {
            // S1 = acc_h1 + acc_h3; publish rows 0..7 into h3 region
#pragma unroll
            for (int i = 0; i < 16; ++i) {
                const float4 v = cb[1024 + i * 64 + e4];
                acc[i].x += v.x; acc[i].y += v.y; acc[i].z += v.z; acc[i].w += v.w;
            }
#pragma unroll
            for (int i = 0; i < 8; ++i)
                cb[1024 + i * 64 + e4] = acc[i];
        }
        __syncthreads();
        {
            float4* po = (float4*)part + (size_t)rid * 1024;  // [16][64] f4
            if (h == 0) {
#pragma unroll
                for (int i = 0; i < 8; ++i) {
                    const float4 v = cb[1024 + i * 64 + e4];  // S1 rows 0..7
                    acc[i].x += v.x; acc[i].y += v.y; acc[i].z += v.z; acc[i].w += v.w;
                    po[i * 64 + e4] = acc[i];
                }
            } else if (h == 1) {
#pragma unroll
                for (int i = 8; i < 16; ++i) {
                    const float4 v = cb[(i - 8) * 64 + e4];   // S0 rows 8..15
                    acc[i].x += v.x; acc[i].y += v.y; acc[i].z += v.z; acc[i].w += v.w;
                    po[i * 64 + e4] = acc[i];
                }
            }
        }
    } else {
        // ---------------- evt transform ----------------
        const int cid = bid - NROLE;    // [0,256)
        const int b   = cid >> 4;
        const int dc  = cid & 15;
        const int d0  = dc * 32;
        const int ty  = evt_type[b];
        const float* Wt = WTT + (size_t)ty * DD * DD;
        const int e4 = t & 127;
        const int s  = t >> 7;          // 2 d-streams
        float4 a = {0.f, 0.f, 0.f, 0.f};
#pragma unroll
        for (int db = 0; db < 32; db += 16) {
            float  em[8];
            float4 wv[8];
#pragma unroll
            for (int i = 0; i < 8; ++i) {
                const int d = d0 + db + s + 2 * i;
                em[i] = evt_emb[b * DD + d];                       // uniform
                wv[i] = ((const float4*)(Wt + (size_t)d * DD))[e4];
            }
#pragma unroll
            for (int i = 0; i < 8; ++i) {
                a.x = fmaf(em[i], wv[i].x, a.x);
                a.y = fmaf(em[i], wv[i].y, a.y);
                a.z = fmaf(em[i], wv[i].z, a.z);
                a.w = fmaf(em[i], wv[i].w, a.w);
            }
        }
        float4* sm4 = (float4*)smem;
        if (s == 1) sm4[e4] = a;
        __syncthreads();
        if (s == 0) {
            const float4 q4 = sm4[e4];
            a.x += q4.x; a.y += q4.y; a.z += q4.z; a.w += q4.w;
            ((float4*)evt_part)[(size_t)cid * 128 + e4] = a;
        }
    }
}

// ---------------------------------------------------------------------------
// Fused tail: per-batch reduction of part (512 partials, 256 per e-half) +
// evt_part (16 chunks), then the scorer MLP — one block per batch b, 1024
// threads. Deterministic fixed-order reduction, no atomics.
// (Byte-identical to the round-6 147.1us tail.)
// ---------------------------------------------------------------------------
__global__ void __launch_bounds__(1024) kernel_tail(
    const float* __restrict__ part,     // [NROLE][16][256]
    const float* __restrict__ evt_part, // [NEVT][512]
    const float* __restrict__ w1,       // [D,64]
    const float* __restrict__ b1,       // [64]
    const float* __restrict__ w2,       // [64,1]
    const float* __restrict__ b2,       // [1]
    float* __restrict__ out)            // [B,1]
{
    __shared__ float4 sm4[2048];        // 32 KB: [0,1024) div, [1024,2048) evt
    __shared__ float  gsm[512];         // graph embedding for this b
    __shared__ float  hred[1024];       // MLP partial reduce
    const int b  = blockIdx.x;
    const int t  = threadIdx.x;
    const int e4 = t & 127;             // f4 col in full 512-e space
    const int g  = t >> 7;              // 8 groups
    const int eh = e4 >> 6;             // which e-half partials to read
    const int ec = e4 & 63;             // f4 col within the half

    // div: for this e4's half, sum 256 (rp,dI) partials (group sums 32)
    const float4* p4  = (const float4*)part;
    const float4* e4p = (const float4*)evt_part;
    float4 s = {0.f, 0.f, 0.f, 0.f};
#pragma unroll
    for (int i = 0; i < 32; ++i) {
        const int m = g * 32 + i;                     // (rp,dI) linear index
        const float4 v = p4[(size_t)(2 * m + eh) * 1024 + b * 64 + ec];
        s.x += v.x; s.y += v.y; s.z += v.z; s.w += v.w;
    }
    sm4[g * 128 + e4] = s;
    // evt: sum 16 d-chunks (group sums 2)
    float4 es = {0.f, 0.f, 0.f, 0.f};
#pragma unroll
    for (int i = 0; i < 2; ++i) {
        const int dc = g * 2 + i;
        const float4 v = e4p[(size_t)(b * 16 + dc) * 128 + e4];
        es.x += v.x; es.y += v.y; es.z += v.z; es.w += v.w;
    }
    sm4[1024 + g * 128 + e4] = es;
    __syncthreads();

    // combine groups, form graph = (div + evt) * 0.5
    if (t < 128) {
        float4 dv = {0.f,0.f,0.f,0.f}, ev = {0.f,0.f,0.f,0.f};
#pragma unroll
        for (int q = 0; q < 8; ++q) {
            const float4 a = sm4[q * 128 + t];
            const float4 c = sm4[1024 + q * 128 + t];
            dv.x += a.x; dv.y += a.y; dv.z += a.z; dv.w += a.w;
            ev.x += c.x; ev.y += c.y; ev.z += c.z; ev.w += c.w;
        }
        float4 gr;
        gr.x = (dv.x + ev.x) * 0.5f;
        gr.y = (dv.y + ev.y) * 0.5f;
        gr.z = (dv.z + ev.z) * 0.5f;
        gr.w = (dv.w + ev.w) * 0.5f;
        ((float4*)gsm)[t] = gr;
    }
    __syncthreads();

    // MLP: h = relu(graph@w1 + b1) ; out = sigmoid(h@w2 + b2)
    {
        const int j  = t & 63;
        const int dq = t >> 6;          // 16 d-groups of 32
        float hp = 0.f;
#pragma unroll 8
        for (int i = 0; i < 32; ++i) {
            const int d = dq * 32 + i;
            hp = fmaf(gsm[d], w1[d * 64 + j], hp);
        }
        hred[t] = hp;
    }
    __syncthreads();
    if (t < 64) {
        float hh = b1[t];
#pragma unroll
        for (int q = 0; q < 16; ++q) hh += hred[q * 64 + t];
        hh = fmaxf(hh, 0.f);
        float v = hh * w2[t];
#pragma unroll
        for (int off = 32; off > 0; off >>= 1) v += __shfl_down(v, off, 64);
        if (t == 0) out[b] = 1.f / (1.f + expf(-(v + b2[0])));
    }
}

// ---------------------------------------------------------------------------
extern "C" void kernel_launch(void* const* d_in, const int* in_sizes, int n_in,
                              void* d_out, int out_size, void* d_ws, size_t ws_size,
                              hipStream_t stream) {
    const float* logits   = (const float*)d_in[0];
    const float* evt_emb  = (const float*)d_in[1];
    const float* arg_emb  = (const float*)d_in[2];
    // d_in[3] arg_padding_num cancels algebraically; unused
    const int*   evt_type = (const int*)d_in[4];
    const float* WRT      = (const float*)d_in[5];
    const float* WTT      = (const float*)d_in[6];
    const float* w1       = (const float*)d_in[7];
    const float* b1       = (const float*)d_in[8];
    const float* w2       = (const float*)d_in[9];
    const float* b2       = (const float*)d_in[10];
    float* out = (float*)d_out;

    float* part     = (float*)d_ws;                      // 512*4096 floats = 8.39 MB
    float* evt_part = part + (size_t)NROLE * 4096;       // 256*512 floats = 512 KB

    hipLaunchKernelGGL(kernel_a, dim3(NROLE + NEVT), dim3(256), 0, stream,
                       logits, arg_emb, WRT, WTT, evt_emb, evt_type, part, evt_part);
    hipLaunchKernelGGL(kernel_tail, dim3(BB), dim3(1024), 0, stream,
                       part, evt_part, w1, b1, w2, b2, out);
}

// Round 9
// 149.813 us; speedup vs baseline: 1.0471x; 1.0471x over previous
//
#include <hip/hip_runtime.h>
#include <math.h>

// Shapes (compile-time)
#define BB 16
#define LL 28
#define RR 64
#define DD 512
#define NROLE 512           // role chunks: (r-pair, 64-d slice, e-half)
#define NEVT  256           // evt chunks: (b, 32-wide d range)
#define F4RR  65536         // DD*DD/4 : r-to-r stride in float4 units
#define PSTRIDE (NROLE * 64)    // f4 stride between b-planes of part

// ---------------------------------------------------------------------------
// Kernel A — EXACT round-6 body (147.1us best) except the part layout is
// transposed to [b][rid][64 f4] so the tail streams contiguously.
// Lessons baked in: no in-kernel global sync (r5: ~250us L2 storms);
// 768 co-resident blocks (r4/r6); e-split parallelism w/o extra traffic (r4);
// k-split per wave -> WRT fetched once per block (r2); NO prefetch guard and
// NO row-split combine (r7/r8: ~9us regression, suspected VGPR spill from
// unroll-extended live ranges).
// ---------------------------------------------------------------------------
__global__ void __launch_bounds__(256, 3) kernel_a(
    const float* __restrict__ logits,   // [B,L,R]
    const float* __restrict__ arg,      // [B,L,D]
    const float* __restrict__ WRT,      // [R,D,D]
    const float* __restrict__ WTT,      // [E,D,D]
    const float* __restrict__ evt_emb,  // [B,1,D]
    const int*   __restrict__ evt_type, // [B]
    float* __restrict__ part,           // [B][NROLE][64] f4  (transposed)
    float* __restrict__ evt_part)       // [NEVT][512]
{
    __shared__ float smem[8192];        // 32 KB (G 8KB, combine 32KB)
    const int t   = threadIdx.x;
    const int bid = blockIdx.x;

    if (bid < NROLE) {
        // -------- role chunk: (r-pair rp, d-slice d0, e-half eh) --------
        const int rid = bid;
        const int rp  = rid >> 4;           // [0,32)
        const int d0  = ((rid >> 1) & 7) * 64;
        const int eh  = rid & 1;

        const float4* WBase = (const float4*)(WRT + ((size_t)(2 * rp) * DD + d0) * DD);

        const int e4    = t & 63;           // f4 col within e-half
        const int h     = t >> 6;           // wave id = k-quarter owner
        const int co    = eh * 64 + e4;     // f4 col within full row
        const int kbase = 16 * h;

        // Prefetch WRT batch 0 (this wave's k-rows 0..7 of r0) BEFORE phase 1.
        float4 w[8];
#pragma unroll
        for (int i = 0; i < 8; ++i)
            w[i] = WBase[(size_t)(kbase + i) * 128 + co];

        // Phase 1: G[rr][row][b], row = d-local in [0,64), b in [0,16).
        {
            const int b  = t >> 4;
            const int d4 = t & 15;          // float4 d-group (coalesced arg)
            const float4* ap = (const float4*)(arg) + (size_t)(b * LL) * 128 + (d0 >> 2) + d4;
            const float2* lp = (const float2*)(logits) + (size_t)(b * LL) * 32 + rp;
            float4 g0 = {0.f,0.f,0.f,0.f}, g1 = {0.f,0.f,0.f,0.f};
#pragma unroll 7
            for (int l = 0; l < LL; ++l) {
                const float4 av = ap[(size_t)l * 128];
                const float2 lg = lp[(size_t)l * 32];   // logits[b,l,2rp..2rp+1]
                g0.x = fmaf(lg.x, av.x, g0.x); g0.y = fmaf(lg.x, av.y, g0.y);
                g0.z = fmaf(lg.x, av.z, g0.z); g0.w = fmaf(lg.x, av.w, g0.w);
                g1.x = fmaf(lg.y, av.x, g1.x); g1.y = fmaf(lg.y, av.y, g1.y);
                g1.z = fmaf(lg.y, av.z, g1.z); g1.w = fmaf(lg.y, av.w, g1.w);
            }
            const int row = 4 * d4;
            smem[       (row + 0) * 16 + b] = g0.x;
            smem[       (row + 1) * 16 + b] = g0.y;
            smem[       (row + 2) * 16 + b] = g0.z;
            smem[       (row + 3) * 16 + b] = g0.w;
            smem[1024 + (row + 0) * 16 + b] = g1.x;
            smem[1024 + (row + 1) * 16 + b] = g1.y;
            smem[1024 + (row + 2) * 16 + b] = g1.z;
            smem[1024 + (row + 3) * 16 + b] = g1.w;
        }
        __syncthreads();

        // Phase 2: 4 macro-batches (rr = mb>>1, 8 k-rows each), reg dbuf.
        float4 acc[16];
#pragma unroll
        for (int i = 0; i < 16; ++i) acc[i] = make_float4(0.f, 0.f, 0.f, 0.f);

        for (int mb = 0; mb < 4; ++mb) {
            const int mbn = (mb + 1) & 3;            // wraps harmlessly at end
            const size_t nb = (size_t)(mbn >> 1) * F4RR;
            const int kn = kbase + (mbn & 1) * 8;
            float4 wn[8];
#pragma unroll
            for (int i = 0; i < 8; ++i)
                wn[i] = WBase[nb + (size_t)(kn + i) * 128 + co];

            const float* Gr = smem + (mb >> 1) * 1024;
            const int k0 = kbase + (mb & 1) * 8;
#pragma unroll
            for (int i = 0; i < 8; ++i) {
                const float* gp = Gr + (k0 + i) * 16;
                const float4 ga = ((const float4*)gp)[0];   // uniform b128 bcast
                const float4 gb = ((const float4*)gp)[1];
                const float4 gc = ((const float4*)gp)[2];
                const float4 gd = ((const float4*)gp)[3];
#define ACC(j, S) \
                acc[j].x = fmaf(S, w[i].x, acc[j].x); \
                acc[j].y = fmaf(S, w[i].y, acc[j].y); \
                acc[j].z = fmaf(S, w[i].z, acc[j].z); \
                acc[j].w = fmaf(S, w[i].w, acc[j].w);
                ACC(0,  ga.x) ACC(1,  ga.y) ACC(2,  ga.z) ACC(3,  ga.w)
                ACC(4,  gb.x) ACC(5,  gb.y) ACC(6,  gb.z) ACC(7,  gb.w)
                ACC(8,  gc.x) ACC(9,  gc.y) ACC(10, gc.z) ACC(11, gc.w)
                ACC(12, gd.x) ACC(13, gd.y) ACC(14, gd.z) ACC(15, gd.w)
#undef ACC
            }
#pragma unroll
            for (int i = 0; i < 8; ++i) w[i] = wn[i];
        }

        // 2-stage combine of the 4 k-quarter waves (G dead after barrier).
        __syncthreads();
        float4* cb = (float4*)smem;                  // 2048 f4 = 32 KB
        if (h >= 2) {
#pragma unroll
            for (int i = 0; i < 16; ++i)
                cb[(h - 2) * 1024 + i * 64 + e4] = acc[i];   // contig: no conflicts
        }
        __syncthreads();
        if (h < 2) {
#pragma unroll
            for (int i = 0; i < 16; ++i) {
                const float4 v = cb[h * 1024 + i * 64 + e4];
                acc[i].x += v.x; acc[i].y += v.y; acc[i].z += v.z; acc[i].w += v.w;
            }
        }
        __syncthreads();
        if (h == 1) {
#pragma unroll
            for (int i = 0; i < 16; ++i)
                cb[i * 64 + e4] = acc[i];
        }
        __syncthreads();
        if (h == 0) {
            float4* p4 = (float4*)part;
#pragma unroll
            for (int i = 0; i < 16; ++i) {
                const float4 v = cb[i * 64 + e4];
                acc[i].x += v.x; acc[i].y += v.y; acc[i].z += v.z; acc[i].w += v.w;
                // transposed: [b=i][rid][e4]  (1 KB contiguous per row store)
                p4[(size_t)i * PSTRIDE + rid * 64 + e4] = acc[i];
            }
        }
    } else {
        // ---------------- evt transform ----------------
        const int cid = bid - NROLE;    // [0,256)
        const int b   = cid >> 4;
        const int dc  = cid & 15;
        const int d0  = dc * 32;
        const int ty  = evt_type[b];
        const float* Wt = WTT + (size_t)ty * DD * DD;
        const int e4 = t & 127;
        const int s  = t >> 7;          // 2 d-streams
        float4 a = {0.f, 0.f, 0.f, 0.f};
#pragma unroll
        for (int db = 0; db < 32; db += 16) {
            float  em[8];
            float4 wv[8];
#pragma unroll
            for (int i = 0; i < 8; ++i) {
                const int d = d0 + db + s + 2 * i;
                em[i] = evt_emb[b * DD + d];                       // uniform
                wv[i] = ((const float4*)(Wt + (size_t)d * DD))[e4];
            }
#pragma unroll
            for (int i = 0; i < 8; ++i) {
                a.x = fmaf(em[i], wv[i].x, a.x);
                a.y = fmaf(em[i], wv[i].y, a.y);
                a.z = fmaf(em[i], wv[i].z, a.z);
                a.w = fmaf(em[i], wv[i].w, a.w);
            }
        }
        float4* sm4 = (float4*)smem;
        if (s == 1) sm4[e4] = a;
        __syncthreads();
        if (s == 0) {
            const float4 q4 = sm4[e4];
            a.x += q4.x; a.y += q4.y; a.z += q4.z; a.w += q4.w;
            ((float4*)evt_part)[(size_t)cid * 128 + e4] = a;
        }
    }
}

// ---------------------------------------------------------------------------
// Fused tail: per-batch reduction of part (512 partials; with the [b][rid][64]
// transpose each block streams its 512 KB SEQUENTIALLY) + evt_part, then the
// scorer MLP — one block per batch b, 1024 threads. Deterministic fixed-order
// reduction, no atomics. (Otherwise byte-identical to round-6's 147.1us tail.)
// ---------------------------------------------------------------------------
__global__ void __launch_bounds__(1024) kernel_tail(
    const float* __restrict__ part,     // [B][NROLE][64] f4
    const float* __restrict__ evt_part, // [NEVT][512]
    const float* __restrict__ w1,       // [D,64]
    const float* __restrict__ b1,       // [64]
    const float* __restrict__ w2,       // [64,1]
    const float* __restrict__ b2,       // [1]
    float* __restrict__ out)            // [B,1]
{
    __shared__ float4 sm4[2048];        // 32 KB: [0,1024) div, [1024,2048) evt
    __shared__ float  gsm[512];         // graph embedding for this b
    __shared__ float  hred[1024];       // MLP partial reduce
    const int b  = blockIdx.x;
    const int t  = threadIdx.x;
    const int e4 = t & 127;             // f4 col in full 512-e space
    const int g  = t >> 7;              // 8 groups
    const int eh = e4 >> 6;             // which e-half partials to read
    const int ec = e4 & 63;             // f4 col within the half

    // div: for this e4's half, sum 256 (rp,dI) partials (group sums 32).
    // Addressing: rid = 2m+eh, addr = b*PSTRIDE + rid*64 + ec -> each group
    // iteration reads a contiguous 2 KB chunk (lanes 0..127 cover 128 f4).
    const float4* p4  = (const float4*)part;
    const float4* e4p = (const float4*)evt_part;
    float4 s = {0.f, 0.f, 0.f, 0.f};
#pragma unroll
    for (int i = 0; i < 32; ++i) {
        const int m = g * 32 + i;                     // (rp,dI) linear index
        const float4 v = p4[(size_t)b * PSTRIDE + (2 * m + eh) * 64 + ec];
        s.x += v.x; s.y += v.y; s.z += v.z; s.w += v.w;
    }
    sm4[g * 128 + e4] = s;
    // evt: sum 16 d-chunks (group sums 2)
    float4 es = {0.f, 0.f, 0.f, 0.f};
#pragma unroll
    for (int i = 0; i < 2; ++i) {
        const int dc = g * 2 + i;
        const float4 v = e4p[(size_t)(b * 16 + dc) * 128 + e4];
        es.x += v.x; es.y += v.y; es.z += v.z; es.w += v.w;
    }
    sm4[1024 + g * 128 + e4] = es;
    __syncthreads();

    // combine groups, form graph = (div + evt) * 0.5
    if (t < 128) {
        float4 dv = {0.f,0.f,0.f,0.f}, ev = {0.f,0.f,0.f,0.f};
#pragma unroll
        for (int q = 0; q < 8; ++q) {
            const float4 a = sm4[q * 128 + t];
            const float4 c = sm4[1024 + q * 128 + t];
            dv.x += a.x; dv.y += a.y; dv.z += a.z; dv.w += a.w;
            ev.x += c.x; ev.y += c.y; ev.z += c.z; ev.w += c.w;
        }
        float4 gr;
        gr.x = (dv.x + ev.x) * 0.5f;
        gr.y = (dv.y + ev.y) * 0.5f;
        gr.z = (dv.z + ev.z) * 0.5f;
        gr.w = (dv.w + ev.w) * 0.5f;
        ((float4*)gsm)[t] = gr;
    }
    __syncthreads();

    // MLP: h = relu(graph@w1 + b1) ; out = sigmoid(h@w2 + b2)
    {
        const int j  = t & 63;
        const int dq = t >> 6;          // 16 d-groups of 32
        float hp = 0.f;
#pragma unroll 8
        for (int i = 0; i < 32; ++i) {
            const int d = dq * 32 + i;
            hp = fmaf(gsm[d], w1[d * 64 + j], hp);
        }
        hred[t] = hp;
    }
    __syncthreads();
    if (t < 64) {
        float hh = b1[t];
#pragma unroll
        for (int q = 0; q < 16; ++q) hh += hred[q * 64 + t];
        hh = fmaxf(hh, 0.f);
        float v = hh * w2[t];
#pragma unroll
        for (int off = 32; off > 0; off >>= 1) v += __shfl_down(v, off, 64);
        if (t == 0) out[b] = 1.f / (1.f + expf(-(v + b2[0])));
    }
}

// ---------------------------------------------------------------------------
extern "C" void kernel_launch(void* const* d_in, const int* in_sizes, int n_in,
                              void* d_out, int out_size, void* d_ws, size_t ws_size,
                              hipStream_t stream) {
    const float* logits   = (const float*)d_in[0];
    const float* evt_emb  = (const float*)d_in[1];
    const float* arg_emb  = (const float*)d_in[2];
    // d_in[3] arg_padding_num cancels algebraically; unused
    const int*   evt_type = (const int*)d_in[4];
    const float* WRT      = (const float*)d_in[5];
    const float* WTT      = (const float*)d_in[6];
    const float* w1       = (const float*)d_in[7];
    const float* b1       = (const float*)d_in[8];
    const float* w2       = (const float*)d_in[9];
    const float* b2       = (const float*)d_in[10];
    float* out = (float*)d_out;

    float* part     = (float*)d_ws;                      // 16*512*64 f4 = 8.39 MB
    float* evt_part = part + (size_t)BB * PSTRIDE * 4;   // 256*512 floats = 512 KB

    hipLaunchKernelGGL(kernel_a, dim3(NROLE + NEVT), dim3(256), 0, stream,
                       logits, arg_emb, WRT, WTT, evt_emb, evt_type, part, evt_part);
    hipLaunchKernelGGL(kernel_tail, dim3(BB), dim3(1024), 0, stream,
                       part, evt_part, w1, b1, w2, b2, out);
}

// Round 10
// 148.127 us; speedup vs baseline: 1.0590x; 1.0114x over previous
//
#include <hip/hip_runtime.h>
#include <math.h>

// Shapes (compile-time)
#define BB 16
#define LL 28
#define RR 64
#define DD 512
#define NROLE 512           // role chunks: (r-pair, 64-d slice, e-half)
#define NEVT  256           // evt chunks: (b, 32-wide d range)
#define F4RR  65536         // DD*DD/4 : r-to-r stride in float4 units

// ---------------------------------------------------------------------------
// Kernel A — round-6 configuration (best measured: 147.1us).
// Lessons baked in across the session:
//  - no in-kernel global sync (r5: ticket tail = ~250us L2 coherence storms)
//  - 768 blocks all co-resident at 3 blocks/CU (r6: fixes 6%-occupancy stall)
//  - e-split for parallelism with zero extra WRT/partial traffic (r4)
//  - per-wave k-split so WRT is fetched exactly once per block (r2)
//  - unguarded wrap-around prefetch + 2-stage combine (r7/r8: "optimizing"
//    these cost ~9us — unroll-extended live ranges; wrap loads are L1-free)
//  - part layout [rid][16][256]: block-contiguous 16KB stores (r9: the
//    [b][rid][64] transpose scattered stores across 2MB planes, +2.7us)
// ---------------------------------------------------------------------------
__global__ void __launch_bounds__(256, 3) kernel_a(
    const float* __restrict__ logits,   // [B,L,R]
    const float* __restrict__ arg,      // [B,L,D]
    const float* __restrict__ WRT,      // [R,D,D]
    const float* __restrict__ WTT,      // [E,D,D]
    const float* __restrict__ evt_emb,  // [B,1,D]
    const int*   __restrict__ evt_type, // [B]
    float* __restrict__ part,           // [NROLE][16][256]
    float* __restrict__ evt_part)       // [NEVT][512]
{
    __shared__ float smem[8192];        // 32 KB (G 8KB, combine 32KB)
    const int t   = threadIdx.x;
    const int bid = blockIdx.x;

    if (bid < NROLE) {
        // -------- role chunk: (r-pair rp, d-slice d0, e-half eh) --------
        const int rid = bid;
        const int rp  = rid >> 4;           // [0,32)
        const int d0  = ((rid >> 1) & 7) * 64;
        const int eh  = rid & 1;

        const float4* WBase = (const float4*)(WRT + ((size_t)(2 * rp) * DD + d0) * DD);

        const int e4    = t & 63;           // f4 col within e-half
        const int h     = t >> 6;           // wave id = k-quarter owner
        const int co    = eh * 64 + e4;     // f4 col within full row
        const int kbase = 16 * h;

        // Prefetch WRT batch 0 (this wave's k-rows 0..7 of r0) BEFORE phase 1.
        float4 w[8];
#pragma unroll
        for (int i = 0; i < 8; ++i)
            w[i] = WBase[(size_t)(kbase + i) * 128 + co];

        // Phase 1: G[rr][row][b], row = d-local in [0,64), b in [0,16).
        {
            const int b  = t >> 4;
            const int d4 = t & 15;          // float4 d-group (coalesced arg)
            const float4* ap = (const float4*)(arg) + (size_t)(b * LL) * 128 + (d0 >> 2) + d4;
            const float2* lp = (const float2*)(logits) + (size_t)(b * LL) * 32 + rp;
            float4 g0 = {0.f,0.f,0.f,0.f}, g1 = {0.f,0.f,0.f,0.f};
#pragma unroll 7
            for (int l = 0; l < LL; ++l) {
                const float4 av = ap[(size_t)l * 128];
                const float2 lg = lp[(size_t)l * 32];   // logits[b,l,2rp..2rp+1]
                g0.x = fmaf(lg.x, av.x, g0.x); g0.y = fmaf(lg.x, av.y, g0.y);
                g0.z = fmaf(lg.x, av.z, g0.z); g0.w = fmaf(lg.x, av.w, g0.w);
                g1.x = fmaf(lg.y, av.x, g1.x); g1.y = fmaf(lg.y, av.y, g1.y);
                g1.z = fmaf(lg.y, av.z, g1.z); g1.w = fmaf(lg.y, av.w, g1.w);
            }
            const int row = 4 * d4;
            smem[       (row + 0) * 16 + b] = g0.x;
            smem[       (row + 1) * 16 + b] = g0.y;
            smem[       (row + 2) * 16 + b] = g0.z;
            smem[       (row + 3) * 16 + b] = g0.w;
            smem[1024 + (row + 0) * 16 + b] = g1.x;
            smem[1024 + (row + 1) * 16 + b] = g1.y;
            smem[1024 + (row + 2) * 16 + b] = g1.z;
            smem[1024 + (row + 3) * 16 + b] = g1.w;
        }
        __syncthreads();

        // Phase 2: 4 macro-batches (rr = mb>>1, 8 k-rows each), reg dbuf.
        float4 acc[16];
#pragma unroll
        for (int i = 0; i < 16; ++i) acc[i] = make_float4(0.f, 0.f, 0.f, 0.f);

        for (int mb = 0; mb < 4; ++mb) {
            const int mbn = (mb + 1) & 3;            // wraps harmlessly at end
            const size_t nb = (size_t)(mbn >> 1) * F4RR;
            const int kn = kbase + (mbn & 1) * 8;
            float4 wn[8];
#pragma unroll
            for (int i = 0; i < 8; ++i)
                wn[i] = WBase[nb + (size_t)(kn + i) * 128 + co];

            const float* Gr = smem + (mb >> 1) * 1024;
            const int k0 = kbase + (mb & 1) * 8;
#pragma unroll
            for (int i = 0; i < 8; ++i) {
                const float* gp = Gr + (k0 + i) * 16;
                const float4 ga = ((const float4*)gp)[0];   // uniform b128 bcast
                const float4 gb = ((const float4*)gp)[1];
                const float4 gc = ((const float4*)gp)[2];
                const float4 gd = ((const float4*)gp)[3];
#define ACC(j, S) \
                acc[j].x = fmaf(S, w[i].x, acc[j].x); \
                acc[j].y = fmaf(S, w[i].y, acc[j].y); \
                acc[j].z = fmaf(S, w[i].z, acc[j].z); \
                acc[j].w = fmaf(S, w[i].w, acc[j].w);
                ACC(0,  ga.x) ACC(1,  ga.y) ACC(2,  ga.z) ACC(3,  ga.w)
                ACC(4,  gb.x) ACC(5,  gb.y) ACC(6,  gb.z) ACC(7,  gb.w)
                ACC(8,  gc.x) ACC(9,  gc.y) ACC(10, gc.z) ACC(11, gc.w)
                ACC(12, gd.x) ACC(13, gd.y) ACC(14, gd.z) ACC(15, gd.w)
#undef ACC
            }
#pragma unroll
            for (int i = 0; i < 8; ++i) w[i] = wn[i];
        }

        // 2-stage combine of the 4 k-quarter waves (G dead after barrier).
        __syncthreads();
        float4* cb = (float4*)smem;                  // 2048 f4 = 32 KB
        if (h >= 2) {
#pragma unroll
            for (int i = 0; i < 16; ++i)
                cb[(h - 2) * 1024 + i * 64 + e4] = acc[i];   // contig: no conflicts
        }
        __syncthreads();
        if (h < 2) {
#pragma unroll
            for (int i = 0; i < 16; ++i) {
                const float4 v = cb[h * 1024 + i * 64 + e4];
                acc[i].x += v.x; acc[i].y += v.y; acc[i].z += v.z; acc[i].w += v.w;
            }
        }
        __syncthreads();
        if (h == 1) {
#pragma unroll
            for (int i = 0; i < 16; ++i)
                cb[i * 64 + e4] = acc[i];
        }
        __syncthreads();
        if (h == 0) {
            float4* po = (float4*)part + (size_t)rid * 1024;  // [16][64] f4
#pragma unroll
            for (int i = 0; i < 16; ++i) {
                const float4 v = cb[i * 64 + e4];
                acc[i].x += v.x; acc[i].y += v.y; acc[i].z += v.z; acc[i].w += v.w;
                po[i * 64 + e4] = acc[i];
            }
        }
    } else {
        // ---------------- evt transform ----------------
        const int cid = bid - NROLE;    // [0,256)
        const int b   = cid >> 4;
        const int dc  = cid & 15;
        const int d0  = dc * 32;
        const int ty  = evt_type[b];
        const float* Wt = WTT + (size_t)ty * DD * DD;
        const int e4 = t & 127;
        const int s  = t >> 7;          // 2 d-streams
        float4 a = {0.f, 0.f, 0.f, 0.f};
#pragma unroll
        for (int db = 0; db < 32; db += 16) {
            float  em[8];
            float4 wv[8];
#pragma unroll
            for (int i = 0; i < 8; ++i) {
                const int d = d0 + db + s + 2 * i;
                em[i] = evt_emb[b * DD + d];                       // uniform
                wv[i] = ((const float4*)(Wt + (size_t)d * DD))[e4];
            }
#pragma unroll
            for (int i = 0; i < 8; ++i) {
                a.x = fmaf(em[i], wv[i].x, a.x);
                a.y = fmaf(em[i], wv[i].y, a.y);
                a.z = fmaf(em[i], wv[i].z, a.z);
                a.w = fmaf(em[i], wv[i].w, a.w);
            }
        }
        float4* sm4 = (float4*)smem;
        if (s == 1) sm4[e4] = a;
        __syncthreads();
        if (s == 0) {
            const float4 q4 = sm4[e4];
            a.x += q4.x; a.y += q4.y; a.z += q4.z; a.w += q4.w;
            ((float4*)evt_part)[(size_t)cid * 128 + e4] = a;
        }
    }
}

// ---------------------------------------------------------------------------
// Fused tail: per-batch reduction of part (512 partials, 256 per e-half) +
// evt_part (16 chunks), then the scorer MLP — one block per batch b, 1024
// threads. Deterministic fixed-order reduction, no atomics.
// ---------------------------------------------------------------------------
__global__ void __launch_bounds__(1024) kernel_tail(
    const float* __restrict__ part,     // [NROLE][16][256]
    const float* __restrict__ evt_part, // [NEVT][512]
    const float* __restrict__ w1,       // [D,64]
    const float* __restrict__ b1,       // [64]
    const float* __restrict__ w2,       // [64,1]
    const float* __restrict__ b2,       // [1]
    float* __restrict__ out)            // [B,1]
{
    __shared__ float4 sm4[2048];        // 32 KB: [0,1024) div, [1024,2048) evt
    __shared__ float  gsm[512];         // graph embedding for this b
    __shared__ float  hred[1024];       // MLP partial reduce
    const int b  = blockIdx.x;
    const int t  = threadIdx.x;
    const int e4 = t & 127;             // f4 col in full 512-e space
    const int g  = t >> 7;              // 8 groups
    const int eh = e4 >> 6;             // which e-half partials to read
    const int ec = e4 & 63;             // f4 col within the half

    // div: for this e4's half, sum 256 (rp,dI) partials (group sums 32)
    const float4* p4  = (const float4*)part;
    const float4* e4p = (const float4*)evt_part;
    float4 s = {0.f, 0.f, 0.f, 0.f};
#pragma unroll
    for (int i = 0; i < 32; ++i) {
        const int m = g * 32 + i;                     // (rp,dI) linear index
        const float4 v = p4[(size_t)(2 * m + eh) * 1024 + b * 64 + ec];
        s.x += v.x; s.y += v.y; s.z += v.z; s.w += v.w;
    }
    sm4[g * 128 + e4] = s;
    // evt: sum 16 d-chunks (group sums 2)
    float4 es = {0.f, 0.f, 0.f, 0.f};
#pragma unroll
    for (int i = 0; i < 2; ++i) {
        const int dc = g * 2 + i;
        const float4 v = e4p[(size_t)(b * 16 + dc) * 128 + e4];
        es.x += v.x; es.y += v.y; es.z += v.z; es.w += v.w;
    }
    sm4[1024 + g * 128 + e4] = es;
    __syncthreads();

    // combine groups, form graph = (div + evt) * 0.5
    if (t < 128) {
        float4 dv = {0.f,0.f,0.f,0.f}, ev = {0.f,0.f,0.f,0.f};
#pragma unroll
        for (int q = 0; q < 8; ++q) {
            const float4 a = sm4[q * 128 + t];
            const float4 c = sm4[1024 + q * 128 + t];
            dv.x += a.x; dv.y += a.y; dv.z += a.z; dv.w += a.w;
            ev.x += c.x; ev.y += c.y; ev.z += c.z; ev.w += c.w;
        }
        float4 gr;
        gr.x = (dv.x + ev.x) * 0.5f;
        gr.y = (dv.y + ev.y) * 0.5f;
        gr.z = (dv.z + ev.z) * 0.5f;
        gr.w = (dv.w + ev.w) * 0.5f;
        ((float4*)gsm)[t] = gr;
    }
    __syncthreads();

    // MLP: h = relu(graph@w1 + b1) ; out = sigmoid(h@w2 + b2)
    {
        const int j  = t & 63;
        const int dq = t >> 6;          // 16 d-groups of 32
        float hp = 0.f;
#pragma unroll 8
        for (int i = 0; i < 32; ++i) {
            const int d = dq * 32 + i;
            hp = fmaf(gsm[d], w1[d * 64 + j], hp);
        }
        hred[t] = hp;
    }
    __syncthreads();
    if (t < 64) {
        float hh = b1[t];
#pragma unroll
        for (int q = 0; q < 16; ++q) hh += hred[q * 64 + t];
        hh = fmaxf(hh, 0.f);
        float v = hh * w2[t];
#pragma unroll
        for (int off = 32; off > 0; off >>= 1) v += __shfl_down(v, off, 64);
        if (t == 0) out[b] = 1.f / (1.f + expf(-(v + b2[0])));
    }
}

// ---------------------------------------------------------------------------
extern "C" void kernel_launch(void* const* d_in, const int* in_sizes, int n_in,
                              void* d_out, int out_size, void* d_ws, size_t ws_size,
                              hipStream_t stream) {
    const float* logits   = (const float*)d_in[0];
    const float* evt_emb  = (const float*)d_in[1];
    const float* arg_emb  = (const float*)d_in[2];
    // d_in[3] arg_padding_num cancels algebraically; unused
    const int*   evt_type = (const int*)d_in[4];
    const float* WRT      = (const float*)d_in[5];
    const float* WTT      = (const float*)d_in[6];
    const float* w1       = (const float*)d_in[7];
    const float* b1       = (const float*)d_in[8];
    const float* w2       = (const float*)d_in[9];
    const float* b2       = (const float*)d_in[10];
    float* out = (float*)d_out;

    float* part     = (float*)d_ws;                      // 512*4096 floats = 8.39 MB
    float* evt_part = part + (size_t)NROLE * 4096;       // 256*512 floats = 512 KB

    hipLaunchKernelGGL(kernel_a, dim3(NROLE + NEVT), dim3(256), 0, stream,
                       logits, arg_emb, WRT, WTT, evt_emb, evt_type, part, evt_part);
    hipLaunchKernelGGL(kernel_tail, dim3(BB), dim3(1024), 0, stream,
                       part, evt_part, w1, b1, w2, b2, out);
}